// Round 1
// baseline (385.819 us; speedup 1.0000x reference)
//
#include <hip/hip_runtime.h>
#include <hip/hip_bf16.h>
#include <stdint.h>

// MoveCenterPts: out = where(MOD & (feat != 0), clip(feat + deltas@COEF.T, 0, LIM), feat)
// COEF rows have <= 2 nonzero entries, all 1.0. MOD/LIM/COEF derive from a static
// layout walk over d in [0, 2217). We encode per-d metadata in one uint:
//   bit0: mod flag
//   bit1: has second delta (wB)
//   bit2: lim is IM_H (720) else IM_W (1280)
//   bits3-5: delta index A (0..7)
//   bits6-8: delta index B (0..7)
//
// Layout segments (TOP_K=1, G=40, N_JOINTS=22), delta idx: RHX=0,RHY=1,LHX=2,LHY=3,OX=4,OY=5,JX=6,JY=7
//   d=0            skip (rh activation)
//   d=1..80        (RHX,OX)/(RHY,OY) alternating
//   d=81,82        (RHX)/(RHY)
//   d=83           skip (lh activation)
//   d=84..163      (LHX,OX)/(LHY,OY)
//   d=164,165      (LHX)/(LHY)
//   d=166,167      (RHX,LHX)/(RHY,LHY)
//   d=168          skip (intersection)
//   d=169..368     groups of 5: {skip,skip,skip,(OX),(OY)}
//   d=369..412     (LHX,JX)/(LHY,JY)
//   d=413..456     (RHX,JX)/(RHY,JY)
//   d=457..2216    (OX,JX)/(OY,JY)
// Totals: 1+80+2+1+80+2+2+1+200+44+44+1760 = 2217.

#define D_FEAT 2217u

__global__ void build_meta_kernel(uint32_t* __restrict__ meta) {
    int d = blockIdx.x * blockDim.x + threadIdx.x;
    if (d >= (int)D_FEAT) return;

    int a = 0, b = 0;
    bool mod = true, hasB = false;

    if (d == 0 || d == 83 || d == 168) {
        mod = false;
    } else if (d <= 80) {
        int o = d - 1;
        if ((o & 1) == 0) { a = 0; b = 4; } else { a = 1; b = 5; }
        hasB = true;
    } else if (d == 81) { a = 0;
    } else if (d == 82) { a = 1;
    } else if (d <= 163) {
        int o = d - 84;
        if ((o & 1) == 0) { a = 2; b = 4; } else { a = 3; b = 5; }
        hasB = true;
    } else if (d == 164) { a = 2;
    } else if (d == 165) { a = 3;
    } else if (d == 166) { a = 0; b = 2; hasB = true;
    } else if (d == 167) { a = 1; b = 3; hasB = true;
    } else if (d <= 368) {
        int o = (d - 169) % 5;
        if (o < 3) { mod = false; }
        else if (o == 3) { a = 4; }
        else { a = 5; }
    } else if (d <= 412) {
        int o = d - 369;
        if ((o & 1) == 0) { a = 2; b = 6; } else { a = 3; b = 7; }
        hasB = true;
    } else if (d <= 456) {
        int o = d - 413;
        if ((o & 1) == 0) { a = 0; b = 6; } else { a = 1; b = 7; }
        hasB = true;
    } else {
        int o = d - 457;
        if ((o & 1) == 0) { a = 4; b = 6; } else { a = 5; b = 7; }
        hasB = true;
    }

    uint32_t limH = (uint32_t)(a & 1);  // odd delta index => y => lim 720
    uint32_t pack = (mod ? 1u : 0u) | (hasB ? 2u : 0u) | (limH << 2)
                  | ((uint32_t)a << 3) | ((uint32_t)b << 6);
    meta[d] = pack;
}

__global__ __launch_bounds__(256) void move_center_pts_kernel(
    const float* __restrict__ feat,
    const float* __restrict__ deltas,
    const uint32_t* __restrict__ meta,
    float* __restrict__ out,
    unsigned n4) {
    unsigned stride = gridDim.x * blockDim.x;
    for (unsigned i4 = blockIdx.x * blockDim.x + threadIdx.x; i4 < n4; i4 += stride) {
        unsigned base = i4 * 4u;
        unsigned t = base / D_FEAT;          // compiler magic-div
        unsigned d = base - t * D_FEAT;
        unsigned t8 = t * 8u;

        const float4 f4 = reinterpret_cast<const float4*>(feat)[i4];
        float fv[4] = {f4.x, f4.y, f4.z, f4.w};
        float ov[4];

        #pragma unroll
        for (int j = 0; j < 4; ++j) {
            uint32_t p = meta[d];
            float dA = deltas[t8 + ((p >> 3) & 7u)];
            float dB = deltas[t8 + ((p >> 6) & 7u)];
            float off = dA + ((p & 2u) ? dB : 0.0f);
            float lim = (p & 4u) ? 720.0f : 1280.0f;
            float f = fv[j];
            float s = fminf(fmaxf(f + off, 0.0f), lim);
            ov[j] = ((p & 1u) && (f != 0.0f)) ? s : f;
            ++d;
            if (d == D_FEAT) { d = 0u; t8 += 8u; }
        }

        float4 o4;
        o4.x = ov[0]; o4.y = ov[1]; o4.z = ov[2]; o4.w = ov[3];
        reinterpret_cast<float4*>(out)[i4] = o4;
    }
}

extern "C" void kernel_launch(void* const* d_in, const int* in_sizes, int n_in,
                              void* d_out, int out_size, void* d_ws, size_t ws_size,
                              hipStream_t stream) {
    const float* feat   = (const float*)d_in[0];   // [T, 2217] f32
    const float* deltas = (const float*)d_in[1];   // [T, 8] f32
    float* out = (float*)d_out;
    uint32_t* meta = (uint32_t*)d_ws;              // 2217 * 4 B scratch

    // rebuild metadata every call (d_ws is re-poisoned before each timed launch)
    build_meta_kernel<<<(D_FEAT + 255) / 256, 256, 0, stream>>>(meta);

    unsigned total = (unsigned)in_sizes[0];        // T * 2217
    unsigned n4 = total / 4u;                      // divisible: T % 8 == 0
    // memory-bound: ~2048 blocks + grid-stride (256 CUs x 8)
    unsigned blocks = (n4 + 255u) / 256u;
    if (blocks > 2048u) blocks = 2048u;
    move_center_pts_kernel<<<blocks, 256, 0, stream>>>(feat, deltas, meta, out, n4);
}

// Round 7
// 373.523 us; speedup vs baseline: 1.0329x; 1.0329x over previous
//
#include <hip/hip_runtime.h>
#include <hip/hip_bf16.h>
#include <stdint.h>

// MoveCenterPts: out = where(MOD & (feat != 0), clip(feat + deltas@COEF.T, 0, LIM), feat)
// COEF rows have <= 2 nonzero entries, all 1.0. Layout is static over d in [0,2217):
//   d=0            skip (rh activation)
//   d=1..80        (RHX,OX)/(RHY,OY) alternating
//   d=81,82        (RHX)/(RHY)
//   d=83           skip (lh activation)
//   d=84..163      (LHX,OX)/(LHY,OY)
//   d=164,165      (LHX)/(LHY)
//   d=166,167      (RHX,LHX)/(RHY,LHY)
//   d=168          skip (intersection)
//   d=169..368     groups of 5: {skip,skip,skip,(OX),(OY)}
//   d=369..412     (LHX,JX)/(LHY,JY)
//   d=413..456     (RHX,JX)/(RHY,JY)
//   d=457..2216    (OX,JX)/(OY,JY)      <-- 79% of elements, pure 2-phase pattern
//
// FAST PATH: groups fully inside [457, 2216] (no row wrap): off = (d odd) ? OX+JX : OY+JY,
// lim = (d odd) ? 1280 : 720, mod always true. 1 float4 delta load replaces 4 meta + 8
// delta scalar loads. Wave-uniform branch (lanes are 256 consecutive elements).
//
// GENERIC PATH (21% of elements, head of each row + wrap groups): packed meta table in
// d_ws (rebuilt each call since ws is re-poisoned):
//   bit0: mod, bit1: hasB, bit2: lim is 720, bits3-5: delta idx A, bits6-8: delta idx B

#define D_FEAT 2217u

__global__ void build_meta_kernel(uint32_t* __restrict__ meta) {
    int d = blockIdx.x * blockDim.x + threadIdx.x;
    if (d >= (int)D_FEAT) return;

    int a = 0, b = 0;
    bool mod = true, hasB = false;

    if (d == 0 || d == 83 || d == 168) {
        mod = false;
    } else if (d <= 80) {
        int o = d - 1;
        if ((o & 1) == 0) { a = 0; b = 4; } else { a = 1; b = 5; }
        hasB = true;
    } else if (d == 81) { a = 0;
    } else if (d == 82) { a = 1;
    } else if (d <= 163) {
        int o = d - 84;
        if ((o & 1) == 0) { a = 2; b = 4; } else { a = 3; b = 5; }
        hasB = true;
    } else if (d == 164) { a = 2;
    } else if (d == 165) { a = 3;
    } else if (d == 166) { a = 0; b = 2; hasB = true;
    } else if (d == 167) { a = 1; b = 3; hasB = true;
    } else if (d <= 368) {
        int o = (d - 169) % 5;
        if (o < 3) { mod = false; }
        else if (o == 3) { a = 4; }
        else { a = 5; }
    } else if (d <= 412) {
        int o = d - 369;
        if ((o & 1) == 0) { a = 2; b = 6; } else { a = 3; b = 7; }
        hasB = true;
    } else if (d <= 456) {
        int o = d - 413;
        if ((o & 1) == 0) { a = 0; b = 6; } else { a = 1; b = 7; }
        hasB = true;
    } else {
        int o = d - 457;
        if ((o & 1) == 0) { a = 4; b = 6; } else { a = 5; b = 7; }
        hasB = true;
    }

    uint32_t limH = (uint32_t)(a & 1);  // odd delta index => y => lim 720
    uint32_t pack = (mod ? 1u : 0u) | (hasB ? 2u : 0u) | (limH << 2)
                  | ((uint32_t)a << 3) | ((uint32_t)b << 6);
    meta[d] = pack;
}

__global__ __launch_bounds__(256) void move_center_pts_kernel(
    const float* __restrict__ feat,
    const float* __restrict__ deltas,
    const uint32_t* __restrict__ meta,
    float* __restrict__ out,
    unsigned n4) {
    unsigned stride = gridDim.x * blockDim.x;
    for (unsigned i4 = blockIdx.x * blockDim.x + threadIdx.x; i4 < n4; i4 += stride) {
        unsigned base = i4 * 4u;
        unsigned t = base / D_FEAT;          // compiler magic-div
        unsigned d = base - t * D_FEAT;

        const float4 f4 = reinterpret_cast<const float4*>(feat)[i4];
        float4 o4;

        if (d >= 457u && d < 2214u) {
            // ---- fast path: tail segment, no wrap, mod always true ----
            // deltas[t*8 + 4..7] = {OX, OY, JX, JY}; byte offset 32t+16 -> 16B aligned
            const float4 dd = *reinterpret_cast<const float4*>(deltas + t * 8u + 4u);
            float offx = dd.x + dd.z;   // OX + JX
            float offy = dd.y + dd.w;   // OY + JY
            bool x0 = (d & 1u) != 0u;   // d odd => x slot
            float offA = x0 ? offx : offy, limA = x0 ? 1280.0f : 720.0f;
            float offB = x0 ? offy : offx, limB = x0 ? 720.0f : 1280.0f;
            float f, s;
            f = f4.x; s = fminf(fmaxf(f + offA, 0.0f), limA); o4.x = (f != 0.0f) ? s : f;
            f = f4.y; s = fminf(fmaxf(f + offB, 0.0f), limB); o4.y = (f != 0.0f) ? s : f;
            f = f4.z; s = fminf(fmaxf(f + offA, 0.0f), limA); o4.z = (f != 0.0f) ? s : f;
            f = f4.w; s = fminf(fmaxf(f + offB, 0.0f), limB); o4.w = (f != 0.0f) ? s : f;
        } else {
            // ---- generic path: row head / wrap groups ----
            unsigned t8 = t * 8u;
            unsigned dd = d;
            float fv[4] = {f4.x, f4.y, f4.z, f4.w};
            float ov[4];
            #pragma unroll
            for (int j = 0; j < 4; ++j) {
                uint32_t p = meta[dd];
                float dA = deltas[t8 + ((p >> 3) & 7u)];
                float dB = deltas[t8 + ((p >> 6) & 7u)];
                float off = dA + ((p & 2u) ? dB : 0.0f);
                float lim = (p & 4u) ? 720.0f : 1280.0f;
                float f = fv[j];
                float s = fminf(fmaxf(f + off, 0.0f), lim);
                ov[j] = ((p & 1u) && (f != 0.0f)) ? s : f;
                ++dd;
                if (dd == D_FEAT) { dd = 0u; t8 += 8u; }
            }
            o4.x = ov[0]; o4.y = ov[1]; o4.z = ov[2]; o4.w = ov[3];
        }

        reinterpret_cast<float4*>(out)[i4] = o4;
    }
}

extern "C" void kernel_launch(void* const* d_in, const int* in_sizes, int n_in,
                              void* d_out, int out_size, void* d_ws, size_t ws_size,
                              hipStream_t stream) {
    const float* feat   = (const float*)d_in[0];   // [T, 2217] f32
    const float* deltas = (const float*)d_in[1];   // [T, 8] f32
    float* out = (float*)d_out;
    uint32_t* meta = (uint32_t*)d_ws;              // 2217 * 4 B scratch

    // rebuild metadata every call (d_ws is re-poisoned before each timed launch)
    build_meta_kernel<<<(D_FEAT + 255) / 256, 256, 0, stream>>>(meta);

    unsigned total = (unsigned)in_sizes[0];        // T * 2217
    unsigned n4 = total / 4u;                      // divisible: T % 8 == 0
    // memory-bound: 2048 blocks (32 waves/CU) + grid-stride
    unsigned blocks = (n4 + 255u) / 256u;
    if (blocks > 2048u) blocks = 2048u;
    move_center_pts_kernel<<<blocks, 256, 0, stream>>>(feat, deltas, meta, out, n4);
}

// Round 8
// 366.552 us; speedup vs baseline: 1.0526x; 1.0190x over previous
//
#include <hip/hip_runtime.h>
#include <hip/hip_bf16.h>
#include <stdint.h>

// MoveCenterPts: out = where(MOD & (feat != 0), clip(feat + deltas@COEF.T, 0, LIM), feat)
// Layout over d in [0,2217) (TOP_K=1, G=40, N_JOINTS=22); delta idx RHX=0..JY=7:
//   d=0 skip | 1..80 (RH,O) pairs | 81,82 (RH) | 83 skip | 84..163 (LH,O) | 164,165 (LH)
//   | 166,167 (RH,LH) | 168 skip | 169..368 {skip,skip,skip,(OX),(OY)} | 369..412 (LH,J)
//   | 413..456 (RH,J) | 457..2216 (OX,JX)/(OY,JY)  <-- 79% of elements, 2-phase
//
// Round-7 measured: 125 us, latency-bound (VALU/VMEM issue ~8 us, HBM ~52 us).
// This round: x4 strided unroll (8 VMEM in flight/wave, counted vmcnt) + nontemporal
// feat loads / out stores (both touched exactly once; keep L3 for feat restore-writes).

#define D_FEAT 2217u
typedef float f32x4 __attribute__((ext_vector_type(4)));

__global__ void build_meta_kernel(uint32_t* __restrict__ meta) {
    int d = blockIdx.x * blockDim.x + threadIdx.x;
    if (d >= (int)D_FEAT) return;

    int a = 0, b = 0;
    bool mod = true, hasB = false;

    if (d == 0 || d == 83 || d == 168) {
        mod = false;
    } else if (d <= 80) {
        int o = d - 1;
        if ((o & 1) == 0) { a = 0; b = 4; } else { a = 1; b = 5; }
        hasB = true;
    } else if (d == 81) { a = 0;
    } else if (d == 82) { a = 1;
    } else if (d <= 163) {
        int o = d - 84;
        if ((o & 1) == 0) { a = 2; b = 4; } else { a = 3; b = 5; }
        hasB = true;
    } else if (d == 164) { a = 2;
    } else if (d == 165) { a = 3;
    } else if (d == 166) { a = 0; b = 2; hasB = true;
    } else if (d == 167) { a = 1; b = 3; hasB = true;
    } else if (d <= 368) {
        int o = (d - 169) % 5;
        if (o < 3) { mod = false; }
        else if (o == 3) { a = 4; }
        else { a = 5; }
    } else if (d <= 412) {
        int o = d - 369;
        if ((o & 1) == 0) { a = 2; b = 6; } else { a = 3; b = 7; }
        hasB = true;
    } else if (d <= 456) {
        int o = d - 413;
        if ((o & 1) == 0) { a = 0; b = 6; } else { a = 1; b = 7; }
        hasB = true;
    } else {
        int o = d - 457;
        if ((o & 1) == 0) { a = 4; b = 6; } else { a = 5; b = 7; }
        hasB = true;
    }

    uint32_t limH = (uint32_t)(a & 1);  // odd delta index => y => lim 720
    uint32_t pack = (mod ? 1u : 0u) | (hasB ? 2u : 0u) | (limH << 2)
                  | ((uint32_t)a << 3) | ((uint32_t)b << 6);
    meta[d] = pack;
}

// Process one float4 group at feature offset d of frame t. dd = deltas[t*8+4..7]
// (prefetched; used only by the fast path).
__device__ __forceinline__ f32x4 process_group(f32x4 f4, f32x4 dd, unsigned t, unsigned d,
                                               const float* __restrict__ deltas,
                                               const uint32_t* __restrict__ meta) {
    f32x4 o4;
    if (d >= 457u && d < 2214u) {
        // fast path: tail segment, no row wrap, mod always true
        float offx = dd.x + dd.z;   // OX + JX
        float offy = dd.y + dd.w;   // OY + JY
        bool x0 = (d & 1u) != 0u;   // d odd => x slot
        float offA = x0 ? offx : offy, limA = x0 ? 1280.0f : 720.0f;
        float offB = x0 ? offy : offx, limB = x0 ? 720.0f : 1280.0f;
        float f, s;
        f = f4.x; s = fminf(fmaxf(f + offA, 0.0f), limA); o4.x = (f != 0.0f) ? s : f;
        f = f4.y; s = fminf(fmaxf(f + offB, 0.0f), limB); o4.y = (f != 0.0f) ? s : f;
        f = f4.z; s = fminf(fmaxf(f + offA, 0.0f), limA); o4.z = (f != 0.0f) ? s : f;
        f = f4.w; s = fminf(fmaxf(f + offB, 0.0f), limB); o4.w = (f != 0.0f) ? s : f;
    } else {
        // generic path: row head / wrap groups (meta-table driven, identical to
        // the measured-correct round-0 logic)
        unsigned t8 = t * 8u;
        unsigned dx = d;
        float fv[4] = {f4.x, f4.y, f4.z, f4.w};
        float ov[4];
        #pragma unroll
        for (int j = 0; j < 4; ++j) {
            uint32_t p = meta[dx];
            float dA = deltas[t8 + ((p >> 3) & 7u)];
            float dB = deltas[t8 + ((p >> 6) & 7u)];
            float off = dA + ((p & 2u) ? dB : 0.0f);
            float lim = (p & 4u) ? 720.0f : 1280.0f;
            float f = fv[j];
            float s = fminf(fmaxf(f + off, 0.0f), lim);
            ov[j] = ((p & 1u) && (f != 0.0f)) ? s : f;
            ++dx;
            if (dx == D_FEAT) { dx = 0u; t8 += 8u; }
        }
        o4.x = ov[0]; o4.y = ov[1]; o4.z = ov[2]; o4.w = ov[3];
    }
    return o4;
}

__global__ __launch_bounds__(256) void move_center_pts_kernel(
    const float* __restrict__ feat,
    const float* __restrict__ deltas,
    const uint32_t* __restrict__ meta,
    float* __restrict__ out,
    unsigned n4) {
    const f32x4* feat4 = reinterpret_cast<const f32x4*>(feat);
    f32x4* out4 = reinterpret_cast<f32x4*>(out);
    unsigned stride = gridDim.x * blockDim.x;
    unsigned i0 = blockIdx.x * blockDim.x + threadIdx.x;

    // main loop: 4 strided groups per iteration -> 8 independent VMEM loads in
    // flight per wave (4 feat dwordx4 + 4 delta dwordx4), counted vmcnt waits.
    for (; i0 + 3u * stride < n4; i0 += 4u * stride) {
        unsigned idx0 = i0, idx1 = i0 + stride, idx2 = i0 + 2u * stride, idx3 = i0 + 3u * stride;
        unsigned b0 = idx0 * 4u, b1 = idx1 * 4u, b2 = idx2 * 4u, b3 = idx3 * 4u;
        unsigned t0 = b0 / D_FEAT, t1 = b1 / D_FEAT, t2 = b2 / D_FEAT, t3 = b3 / D_FEAT;
        unsigned d0 = b0 - t0 * D_FEAT, d1 = b1 - t1 * D_FEAT,
                 d2 = b2 - t2 * D_FEAT, d3 = b3 - t3 * D_FEAT;

        // issue all loads up front (feat nontemporal: read-once)
        f32x4 f0 = __builtin_nontemporal_load(feat4 + idx0);
        f32x4 dd0 = *reinterpret_cast<const f32x4*>(deltas + t0 * 8u + 4u);
        f32x4 f1 = __builtin_nontemporal_load(feat4 + idx1);
        f32x4 dd1 = *reinterpret_cast<const f32x4*>(deltas + t1 * 8u + 4u);
        f32x4 f2 = __builtin_nontemporal_load(feat4 + idx2);
        f32x4 dd2 = *reinterpret_cast<const f32x4*>(deltas + t2 * 8u + 4u);
        f32x4 f3 = __builtin_nontemporal_load(feat4 + idx3);
        f32x4 dd3 = *reinterpret_cast<const f32x4*>(deltas + t3 * 8u + 4u);

        f32x4 o0 = process_group(f0, dd0, t0, d0, deltas, meta);
        __builtin_nontemporal_store(o0, out4 + idx0);
        f32x4 o1 = process_group(f1, dd1, t1, d1, deltas, meta);
        __builtin_nontemporal_store(o1, out4 + idx1);
        f32x4 o2 = process_group(f2, dd2, t2, d2, deltas, meta);
        __builtin_nontemporal_store(o2, out4 + idx2);
        f32x4 o3 = process_group(f3, dd3, t3, d3, deltas, meta);
        __builtin_nontemporal_store(o3, out4 + idx3);
    }

    // remainder: up to 3 strided groups
    for (; i0 < n4; i0 += stride) {
        unsigned b = i0 * 4u;
        unsigned t = b / D_FEAT;
        unsigned d = b - t * D_FEAT;
        f32x4 f = __builtin_nontemporal_load(feat4 + i0);
        f32x4 dd = *reinterpret_cast<const f32x4*>(deltas + t * 8u + 4u);
        f32x4 o = process_group(f, dd, t, d, deltas, meta);
        __builtin_nontemporal_store(o, out4 + i0);
    }
}

extern "C" void kernel_launch(void* const* d_in, const int* in_sizes, int n_in,
                              void* d_out, int out_size, void* d_ws, size_t ws_size,
                              hipStream_t stream) {
    const float* feat   = (const float*)d_in[0];   // [T, 2217] f32
    const float* deltas = (const float*)d_in[1];   // [T, 8] f32
    float* out = (float*)d_out;
    uint32_t* meta = (uint32_t*)d_ws;              // 2217 * 4 B scratch

    // rebuild metadata every call (d_ws is re-poisoned before each timed launch)
    build_meta_kernel<<<(D_FEAT + 255) / 256, 256, 0, stream>>>(meta);

    unsigned total = (unsigned)in_sizes[0];        // T * 2217
    unsigned n4 = total / 4u;                      // divisible: T % 8 == 0
    // memory-bound: 2048 blocks (32 waves/CU) + grid-stride, ~6.6 unrolled iters/thread
    unsigned blocks = (n4 + 255u) / 256u;
    if (blocks > 2048u) blocks = 2048u;
    move_center_pts_kernel<<<blocks, 256, 0, stream>>>(feat, deltas, meta, out, n4);
}